// Round 13
// baseline (413.631 us; speedup 1.0000x reference)
//
#include <hip/hip_runtime.h>
#include <hip/hip_bf16.h>
#include <math.h>

#define BB 8
#define NN 2048
#define FF 64
#define DD 6
#define NSAMP 64
#define TOPK 16
#define NHEAD 8
#define HD 8
#define NLAYER 2
#define EPSF 1e-5f
#define R2 0.09f

typedef short short8 __attribute__((ext_vector_type(8)));
typedef float f32x4 __attribute__((ext_vector_type(4)));
typedef unsigned uint4v __attribute__((ext_vector_type(4)));
typedef unsigned int u32;

// split-pack: u32 = (bf16_hi << 16) | bf16_lo, both RNE. x ≈ hi + lo, err ~2^-16 rel.
__device__ inline unsigned pk2(float x) {
  unsigned b = __float_as_uint(x);
  unsigned hi = (b + 0x7fffu + ((b >> 16) & 1u)) >> 16;
  float r = x - __uint_as_float(hi << 16);
  unsigned c = __float_as_uint(r);
  unsigned lo = (c + 0x7fffu + ((c >> 16) & 1u)) >> 16;
  return (hi << 16) | lo;
}

__device__ inline unsigned short bf16r(float x) {  // RNE bf16
  unsigned b = __float_as_uint(x);
  return (unsigned short)((b + 0x7fffu + ((b >> 16) & 1u)) >> 16);
}

// async global->LDS, 16B per lane (dest = wave-uniform base + lane*16)
__device__ __forceinline__ void gl16(const void* g, void* l) {
  __builtin_amdgcn_global_load_lds((const __attribute__((address_space(1))) u32*)g,
                                   (__attribute__((address_space(3))) u32*)l, 16, 0, 0);
}

// ---- fused prologue: transpose + FFN weight image + qkv/proj weight packs ----
__global__ void k_prep(const float* __restrict__ sv, float* __restrict__ x,
                       const float* __restrict__ w1, const float* __restrict__ w2,
                       unsigned short* __restrict__ img,
                       const float* __restrict__ win, unsigned short* __restrict__ wqh,
                       unsigned short* __restrict__ wql,
                       const float* __restrict__ wout, unsigned short* __restrict__ woh,
                       unsigned short* __restrict__ wol) {
  int i = blockIdx.x * 256 + threadIdx.x;   // [0, 1048576)
  {  // transpose sortvec (B,1,F,N) -> x (B,N,F)
    int f = i % FF;
    int n = (i / FF) % NN;
    int b = i / (FF * NN);
    x[i] = sv[(b * FF + f) * NN + n];
  }
  {  // FFN weight image (pre-swizzled per-chunk LDS byte image)
    int e = i & 4095;
    int plane = (i >> 12) & 3;
    int chg = (i >> 14) & 31;
    int l = i >> 19;
    int r = e >> 6, sh = (e >> 3) & 7, inner = e & 7;
    int s = sh ^ (r & 7);
    float v;
    if (plane < 2) v = w1[((size_t)(l * 2048 + chg * 64 + r)) * 64 + s * 8 + inner];
    else           v = w2[((size_t)(l * 64 + r)) * 2048 + chg * 64 + s * 8 + inner];
    unsigned p = pk2(v);
    img[i] = (unsigned short)((plane & 1) ? (p & 0xffffu) : (p >> 16));
  }
  if (i < NLAYER * 192 * 64) {
    unsigned p = pk2(win[i]);
    wqh[i] = (unsigned short)(p >> 16);
    wql[i] = (unsigned short)(p & 0xffffu);
  }
  if (i < NLAYER * 64 * 64) {
    unsigned p = pk2(wout[i]);
    woh[i] = (unsigned short)(p >> 16);
    wol[i] = (unsigned short)(p & 0xffffu);
  }
}

// ---- qkv v4: split-bf16 MFMA GEMM, no input staging. ----
__global__ void __launch_bounds__(256)
k_qkv4(const float* __restrict__ x, const unsigned short* __restrict__ wqh,
       const unsigned short* __restrict__ wql, const float* __restrict__ bin,
       float* __restrict__ qbuf, uint4* __restrict__ kp4, uint4* __restrict__ vp4) {
  __shared__ __attribute__((aligned(16))) unsigned short l16[64 * 72];
  int row0 = blockIdx.x * 64, y = blockIdx.y, col0 = y * 64;
  int t = threadIdx.x, lane = t & 63, w = t >> 6;
  int nIdx = lane & 15, lq = lane >> 4;
  short8 axh[2], axl[2];
  #pragma unroll
  for (int kbi = 0; kbi < 2; ++kbi) {
    const float* xr = x + (size_t)(row0 + w * 16 + nIdx) * 64 + kbi * 32 + lq * 8;
    #pragma unroll
    for (int j = 0; j < 8; ++j) {
      unsigned p = pk2(xr[j]);
      axh[kbi][j] = (short)(p >> 16);
      axl[kbi][j] = (short)(p & 0xffffu);
    }
  }
  f32x4 acc[4];
  #pragma unroll
  for (int tn = 0; tn < 4; ++tn) acc[tn] = (f32x4){0.f, 0.f, 0.f, 0.f};
  #pragma unroll
  for (int kbi = 0; kbi < 2; ++kbi)
    #pragma unroll
    for (int tn = 0; tn < 4; ++tn) {
      size_t wo = (size_t)(col0 + tn * 16 + nIdx) * 64 + kbi * 32 + lq * 8;
      short8 bh = *(const short8*)(wqh + wo);
      short8 bl = *(const short8*)(wql + wo);
      acc[tn] = __builtin_amdgcn_mfma_f32_16x16x32_bf16(axh[kbi], bh, acc[tn], 0, 0, 0);
      acc[tn] = __builtin_amdgcn_mfma_f32_16x16x32_bf16(axh[kbi], bl, acc[tn], 0, 0, 0);
      acc[tn] = __builtin_amdgcn_mfma_f32_16x16x32_bf16(axl[kbi], bh, acc[tn], 0, 0, 0);
    }
  int b = row0 >> 11, n0 = row0 & (NN - 1);
  if (y == 0) {
    #pragma unroll
    for (int tn = 0; tn < 4; ++tn)
      #pragma unroll
      for (int r = 0; r < 4; ++r) {
        int c = tn * 16 + nIdx;
        qbuf[(size_t)(row0 + w * 16 + lq * 4 + r) * 64 + c] = acc[tn][r] + bin[c];
      }
    return;
  }
  if (y == 1) {
    #pragma unroll
    for (int tn = 0; tn < 4; ++tn)
      #pragma unroll
      for (int r = 0; r < 4; ++r) {
        int c = tn * 16 + nIdx;
        l16[(w * 16 + lq * 4 + r) * 72 + c] = bf16r(acc[tn][r] + bin[64 + c]);
      }
    __syncthreads();
    #pragma unroll
    for (int i = 0; i < 2; ++i) {
      int idx = t + i * 256;
      int h = idx >> 6, tok = idx & 63;
      uint4 v = *(const uint4*)(l16 + tok * 72 + h * 8);
      kp4[(size_t)(b * NHEAD + h) * NN + n0 + tok] = v;
    }
  } else {
    #pragma unroll
    for (int tn = 0; tn < 4; ++tn)
      #pragma unroll
      for (int r = 0; r < 4; ++r) {
        int c = tn * 16 + nIdx;
        l16[c * 72 + (w * 16 + lq * 4 + r)] = bf16r(acc[tn][r] + bin[128 + c]);  // transposed
      }
    __syncthreads();
    #pragma unroll
    for (int i = 0; i < 2; ++i) {
      int idx = t + i * 256;
      int c = idx >> 3, seg = idx & 7;
      uint4 v = *(const uint4*)(l16 + c * 72 + seg * 8);
      vp4[(size_t)(b * 64 + c) * (NN / 8) + (n0 >> 3) + seg] = v;
    }
  }
}

// ---- attention v11: swapped-operand flash (permlane32_swap redistribution) ----
__global__ void __launch_bounds__(256, 8)
k_attn11(const float* __restrict__ q, const uint4* __restrict__ kp4,
         const unsigned* __restrict__ vp32, float* __restrict__ a) {
  __shared__ uint4 kb4[256];                                            // 4 KB
  __shared__ __attribute__((aligned(16))) unsigned short vb16[9 * 264]; // 4.6 KB
  int t = threadIdx.x;
  int lane = t & 63, w = t >> 6;
  int nIdx = lane & 15, lq = lane >> 4;
  int h = blockIdx.y, b = blockIdx.z;
  int qwb = blockIdx.x * 64 + w * 16;
  int bh = b * NHEAD + h;
  const float kf = 0.35355339059327373f * 1.4426950408889634f;  // scale*log2e
  short8 qF = {0, 0, 0, 0, 0, 0, 0, 0};
  if (lq == 0) {
    const float* qr = q + ((size_t)(b * NN + qwb + nIdx)) * 64 + h * HD;
    #pragma unroll
    for (int j = 0; j < 8; ++j) qF[j] = (short)bf16r(qr[j] * kf);
  }
  f32x4 acc0 = {0.f, 0.f, 0.f, 0.f};
  f32x4 acc1 = {0.f, 0.f, 0.f, 0.f};
  const uint4* kbase = kp4 + (size_t)bh * NN;
  const unsigned* vbase = vp32 + (size_t)bh * HD * (NN / 2);
  int vn = nIdx < 9 ? nIdx : 8;
  int voff = ((lq & 1) << 2) + ((lq >> 1) << 4);  // key-group base per quad
  if (t < 132) ((unsigned*)(vb16 + 8 * 264))[t] = 0x3f803f80u;
  uint4 kreg = kbase[t];
  unsigned vreg[4];
  #pragma unroll
  for (int i = 0; i < 4; ++i) {
    int g = t + i * 256;
    vreg[i] = vbase[(g >> 7) * (NN / 2) + (g & 127)];
  }
  for (int kc = 0; kc < NN; kc += 256) {
    __syncthreads();
    kb4[t] = kreg;
    #pragma unroll
    for (int i = 0; i < 4; ++i) {
      int g = t + i * 256;
      ((unsigned*)vb16)[(g >> 7) * 132 + (g & 127)] = vreg[i];
    }
    __syncthreads();
    if (kc + 256 < NN) {
      kreg = kbase[kc + 256 + t];
      #pragma unroll
      for (int i = 0; i < 4; ++i) {
        int g = t + i * 256;
        vreg[i] = vbase[(g >> 7) * (NN / 2) + ((kc + 256) >> 1) + (g & 127)];
      }
    }
    #pragma unroll
    for (int s = 0; s < 8; ++s) {
      int kb = s * 32;
      unsigned pk_[4];
      #pragma unroll
      for (int half = 0; half < 2; ++half) {
        int key = kb + half * 16 + nIdx;
        short8 aK = *(const short8*)(kb4 + key);  // unmasked: k>=8 lanes * 0
        f32x4 c = {0.f, 0.f, 0.f, 0.f};
        __builtin_amdgcn_s_setprio(1);
        c = __builtin_amdgcn_mfma_f32_16x16x32_bf16(aK, qF, c, 0, 0, 0);
        __builtin_amdgcn_s_setprio(0);
        float p0 = __builtin_amdgcn_exp2f(c[0]);
        float p1 = __builtin_amdgcn_exp2f(c[1]);
        float p2 = __builtin_amdgcn_exp2f(c[2]);
        float p3 = __builtin_amdgcn_exp2f(c[3]);
        unsigned r0, r1;
        asm("v_cvt_pk_bf16_f32 %0, %1, %2" : "=v"(r0) : "v"(p0), "v"(p1));
        asm("v_cvt_pk_bf16_f32 %0, %1, %2" : "=v"(r1) : "v"(p2), "v"(p3));
        pk_[half * 2]     = r0;
        pk_[half * 2 + 1] = r1;
      }
      unsigned a02 = pk_[0], b02 = pk_[2];
      unsigned a13 = pk_[1], b13 = pk_[3];
      asm("v_permlane32_swap_b32 %0, %1" : "+v"(a02), "+v"(b02));
      asm("v_permlane32_swap_b32 %0, %1" : "+v"(a13), "+v"(b13));
      uint4v bw;
      bw[0] = a02;
      bw[1] = a13;
      bw[2] = b02;
      bw[3] = b13;
      short8 bP = *(short8*)&bw;
      int vo = vn * 264 + kb + voff;
      uint2 v0 = *(const uint2*)(vb16 + vo);
      uint2 v1 = *(const uint2*)(vb16 + vo + 8);
      uint4v av;
      av[0] = v0.x; av[1] = v0.y; av[2] = v1.x; av[3] = v1.y;
      short8 aV = *(short8*)&av;
      __builtin_amdgcn_s_setprio(1);
      if (s & 1) acc1 = __builtin_amdgcn_mfma_f32_16x16x32_bf16(aV, bP, acc1, 0, 0, 0);
      else       acc0 = __builtin_amdgcn_mfma_f32_16x16x32_bf16(aV, bP, acc0, 0, 0, 0);
      __builtin_amdgcn_s_setprio(0);
    }
  }
  f32x4 acc;
  acc[0] = acc0[0] + acc1[0];
  acc[1] = acc0[1] + acc1[1];
  acc[2] = acc0[2] + acc1[2];
  acc[3] = acc0[3] + acc1[3];
  float lr = __shfl(acc[0], 32 + nIdx);
  if (lq < 2) {
    int row = qwb + nIdx;
    float4 o;
    o.x = acc[0] / lr; o.y = acc[1] / lr; o.z = acc[2] / lr; o.w = acc[3] / lr;
    *(float4*)(a + ((size_t)(b * NN + row)) * 64 + h * HD + lq * 4) = o;
  }
}

// ------- proj v3: split-bf16 MFMA + residual + LN in MFMA C-layout. No LDS. ----
__global__ void __launch_bounds__(256)
k_proj3(const float* __restrict__ a, const unsigned short* __restrict__ woh,
        const unsigned short* __restrict__ wol, const float* __restrict__ bout,
        const float* __restrict__ g, const float* __restrict__ be,
        float* __restrict__ x) {
  int row0 = blockIdx.x * 64;
  int t = threadIdx.x, lane = t & 63, w = t >> 6;
  int nIdx = lane & 15, lq = lane >> 4;
  short8 axh[2], axl[2];
  #pragma unroll
  for (int kbi = 0; kbi < 2; ++kbi) {
    const float* ar = a + (size_t)(row0 + w * 16 + nIdx) * 64 + kbi * 32 + lq * 8;
    #pragma unroll
    for (int j = 0; j < 8; ++j) {
      unsigned p = pk2(ar[j]);
      axh[kbi][j] = (short)(p >> 16);
      axl[kbi][j] = (short)(p & 0xffffu);
    }
  }
  f32x4 acc[4];
  #pragma unroll
  for (int tn = 0; tn < 4; ++tn) acc[tn] = (f32x4){0.f, 0.f, 0.f, 0.f};
  #pragma unroll
  for (int kbi = 0; kbi < 2; ++kbi)
    #pragma unroll
    for (int tn = 0; tn < 4; ++tn) {
      size_t wo = (size_t)(tn * 16 + nIdx) * 64 + kbi * 32 + lq * 8;
      short8 bh = *(const short8*)(woh + wo);
      short8 bl = *(const short8*)(wol + wo);
      acc[tn] = __builtin_amdgcn_mfma_f32_16x16x32_bf16(axh[kbi], bh, acc[tn], 0, 0, 0);
      acc[tn] = __builtin_amdgcn_mfma_f32_16x16x32_bf16(axh[kbi], bl, acc[tn], 0, 0, 0);
      acc[tn] = __builtin_amdgcn_mfma_f32_16x16x32_bf16(axl[kbi], bh, acc[tn], 0, 0, 0);
    }
  #pragma unroll
  for (int r = 0; r < 4; ++r) {
    int row = row0 + w * 16 + lq * 4 + r;
    float val[4], s = 0.f, sq = 0.f;
    #pragma unroll
    for (int tn = 0; tn < 4; ++tn) {
      int c = tn * 16 + nIdx;
      val[tn] = x[(size_t)row * 64 + c] + bout[c] + acc[tn][r];
      s += val[tn]; sq += val[tn] * val[tn];
    }
    #pragma unroll
    for (int off = 1; off < 16; off <<= 1) { s += __shfl_xor(s, off); sq += __shfl_xor(sq, off); }
    float mean = s * (1.f / 64.f);
    float var = sq * (1.f / 64.f) - mean * mean;
    float rstd = rsqrtf(var + EPSF);
    #pragma unroll
    for (int tn = 0; tn < 4; ++tn) {
      int c = tn * 16 + nIdx;
      x[(size_t)row * 64 + c] = (val[tn] - mean) * rstd * g[c] + be[c];
    }
  }
}

// ------- FFN v8: v7 + s_setprio around MFMA clusters (T5) ----
__global__ void __launch_bounds__(256, 2)
k_ffn8(const float* __restrict__ x, const char* __restrict__ img,
       const float* __restrict__ b1, float* __restrict__ part) {
  __shared__ __attribute__((aligned(16))) char W1b[2][16384];
  __shared__ __attribute__((aligned(16))) char W2b[16384];
  __shared__ __attribute__((aligned(16))) unsigned short hpl[2][128 * 64];
  int row0 = blockIdx.x * 128;
  int ks = blockIdx.y, kc = ks * 512;
  int t = threadIdx.x, lane = t & 63, wv = t >> 6;
  int lm = lane & 15, lq = lane >> 4;
  const char* ibase = img + (size_t)ks * 8 * 32768;

  short8 axh[2][2], axl[2][2];
  #pragma unroll
  for (int m = 0; m < 2; ++m)
    #pragma unroll
    for (int kbi = 0; kbi < 2; ++kbi) {
      const float* xr = x + (size_t)(row0 + m * 64 + wv * 16 + lm) * 64 + kbi * 32 + lq * 8;
      #pragma unroll
      for (int j = 0; j < 8; ++j) {
        unsigned p = pk2(xr[j]);
        axh[m][kbi][j] = (short)(p >> 16);
        axl[m][kbi][j] = (short)(p & 0xffffu);
      }
    }
  float bv[8][4];
  #pragma unroll
  for (int ch = 0; ch < 8; ++ch)
    #pragma unroll
    for (int tn = 0; tn < 4; ++tn)
      bv[ch][tn] = b1[kc + ch * 64 + tn * 16 + lm];
  asm volatile("s_waitcnt vmcnt(0)" ::: "memory");
  __builtin_amdgcn_sched_barrier(0);
  #pragma unroll
  for (int i = 0; i < 4; ++i)
    gl16(ibase + i * 4096 + t * 16, &W1b[0][i * 4096 + t * 16]);

  f32x4 acc[2][4];
  #pragma unroll
  for (int m = 0; m < 2; ++m)
    #pragma unroll
    for (int tn = 0; tn < 4; ++tn) acc[m][tn] = (f32x4){0.f, 0.f, 0.f, 0.f};

  #pragma unroll
  for (int ch = 0; ch < 8; ++ch) {
    const int p = ch & 1;
    const char* cbase = ibase + ch * 32768;
    #pragma unroll
    for (int i = 0; i < 4; ++i)
      gl16(cbase + 16384 + i * 4096 + t * 16, &W2b[i * 4096 + t * 16]);
    if (ch < 7) {
      #pragma unroll
      for (int i = 0; i < 4; ++i)
        gl16(cbase + 32768 + i * 4096 + t * 16, &W1b[p ^ 1][i * 4096 + t * 16]);
    }
    if (ch < 7) { asm volatile("s_waitcnt vmcnt(8)" ::: "memory"); }
    else        { asm volatile("s_waitcnt vmcnt(4)" ::: "memory"); }
    __builtin_amdgcn_sched_barrier(0);
    __builtin_amdgcn_s_barrier();
    __builtin_amdgcn_sched_barrier(0);
    const char* P0h = W1b[p];
    const char* P0l = W1b[p] + 8192;
    f32x4 h4[2][4];
    #pragma unroll
    for (int m = 0; m < 2; ++m)
      #pragma unroll
      for (int tn = 0; tn < 4; ++tn) h4[m][tn] = (f32x4){0.f, 0.f, 0.f, 0.f};
    __builtin_amdgcn_s_setprio(1);
    #pragma unroll
    for (int kbi = 0; kbi < 2; ++kbi) {
      int sw = (((kbi * 4 + lq) ^ (lm & 7)) << 4);
      #pragma unroll
      for (int tn = 0; tn < 4; ++tn) {
        int brow = tn * 16 + lm;
        short8 bhi = *(const short8*)(P0h + brow * 128 + sw);
        short8 blo = *(const short8*)(P0l + brow * 128 + sw);
        #pragma unroll
        for (int m = 0; m < 2; ++m) {
          h4[m][tn] = __builtin_amdgcn_mfma_f32_16x16x32_bf16(axh[m][kbi], bhi, h4[m][tn], 0, 0, 0);
          h4[m][tn] = __builtin_amdgcn_mfma_f32_16x16x32_bf16(axh[m][kbi], blo, h4[m][tn], 0, 0, 0);
          h4[m][tn] = __builtin_amdgcn_mfma_f32_16x16x32_bf16(axl[m][kbi], bhi, h4[m][tn], 0, 0, 0);
        }
      }
    }
    __builtin_amdgcn_s_setprio(0);
    #pragma unroll
    for (int m = 0; m < 2; ++m)
      #pragma unroll
      for (int tn = 0; tn < 4; ++tn)
        #pragma unroll
        for (int r = 0; r < 4; ++r) {
          float hv = fmaxf(h4[m][tn][r] + bv[ch][tn], 0.f);
          unsigned u = __float_as_uint(hv);
          float resid = hv - __uint_as_float(u & 0xffff0000u);
          unsigned c2 = __float_as_uint(resid);
          int hrow = m * 64 + wv * 16 + lq * 4 + r, hcol = tn * 16 + lm;
          int off = hrow * 128 + (((hcol >> 3) ^ (hrow & 7)) << 4) + ((hcol & 7) << 1);
          *(unsigned short*)((char*)hpl[0] + off) = (unsigned short)(u >> 16);
          *(unsigned short*)((char*)hpl[1] + off) =
              (unsigned short)((c2 + 0x7fffu + ((c2 >> 16) & 1u)) >> 16);
        }
    if (ch < 7) { asm volatile("s_waitcnt vmcnt(4)" ::: "memory"); }
    else        { asm volatile("s_waitcnt vmcnt(0)" ::: "memory"); }
    __builtin_amdgcn_sched_barrier(0);
    __builtin_amdgcn_s_barrier();
    __builtin_amdgcn_sched_barrier(0);
    const char* P1h = W2b;
    const char* P1l = W2b + 8192;
    __builtin_amdgcn_s_setprio(1);
    #pragma unroll
    for (int kbi = 0; kbi < 2; ++kbi) {
      short8 a2h[2], a2l[2];
      #pragma unroll
      for (int m = 0; m < 2; ++m) {
        int arow = m * 64 + wv * 16 + lm;
        int swa = (((kbi * 4 + lq) ^ (arow & 7)) << 4);
        a2h[m] = *(const short8*)((const char*)hpl[0] + arow * 128 + swa);
        a2l[m] = *(const short8*)((const char*)hpl[1] + arow * 128 + swa);
      }
      int swb = (((kbi * 4 + lq) ^ (lm & 7)) << 4);
      #pragma unroll
      for (int tn = 0; tn < 4; ++tn) {
        int brow = tn * 16 + lm;
        short8 bhi = *(const short8*)(P1h + brow * 128 + swb);
        short8 blo = *(const short8*)(P1l + brow * 128 + swb);
        #pragma unroll
        for (int m = 0; m < 2; ++m) {
          acc[m][tn] = __builtin_amdgcn_mfma_f32_16x16x32_bf16(a2h[m], bhi, acc[m][tn], 0, 0, 0);
          acc[m][tn] = __builtin_amdgcn_mfma_f32_16x16x32_bf16(a2h[m], blo, acc[m][tn], 0, 0, 0);
          acc[m][tn] = __builtin_amdgcn_mfma_f32_16x16x32_bf16(a2l[m], bhi, acc[m][tn], 0, 0, 0);
        }
      }
    }
    __builtin_amdgcn_s_setprio(0);
    __builtin_amdgcn_s_barrier();
    __builtin_amdgcn_sched_barrier(0);
  }
  float* fb = (float*)hpl;
  #pragma unroll
  for (int m = 0; m < 2; ++m)
    #pragma unroll
    for (int tn = 0; tn < 4; ++tn)
      #pragma unroll
      for (int r = 0; r < 4; ++r) {
        int row = m * 64 + wv * 16 + lq * 4 + r;
        int col = (tn * 16 + lm) ^ ((row & 7) << 2);
        fb[row * 64 + col] = acc[m][tn][r];
      }
  __syncthreads();
  float* pb = part + (size_t)ks * (BB * NN * 64);
  #pragma unroll
  for (int i = 0; i < 8; ++i) {
    int idx = t * 4 + i * 1024;
    int row = idx >> 6, c0 = idx & 63;
    int c0s = c0 ^ ((row & 7) << 2);
    float4 v = *(const float4*)(fb + row * 64 + c0s);
    *(float4*)(pb + (size_t)(row0 + row) * 64 + c0) = v;
  }
}

// ------- combine 4 partials + residual + b2 + LN; one wave per row ---------
__global__ void k_ffn_ln(const float* __restrict__ part, const float* __restrict__ b2,
                         const float* __restrict__ g, const float* __restrict__ be,
                         float* __restrict__ x) {
  int row = blockIdx.x * 4 + (threadIdx.x >> 6);
  int j = threadIdx.x & 63;
  size_t o = (size_t)row * 64 + j;
  const size_t S = (size_t)BB * NN * 64;
  float val = x[o] + b2[j] + ((part[o] + part[o + S]) + (part[o + 2 * S] + part[o + 3 * S]));
  float s = val;
  for (int off = 32; off; off >>= 1) s += __shfl_xor(s, off);
  s *= (1.f / 64.f);
  float d = val - s;
  float v = d * d;
  for (int off = 32; off; off >>= 1) v += __shfl_xor(v, off);
  v *= (1.f / 64.f);
  x[o] = d * rsqrtf(v + EPSF) * g[j] + be[j];
}

// ------- score head tiled ----------
__global__ void k_fg2(const float* __restrict__ x,
                      const float* __restrict__ w0, const float* __restrict__ b0, const float* __restrict__ bn0,
                      const float* __restrict__ w1, const float* __restrict__ b1, const float* __restrict__ bn1,
                      const float* __restrict__ w2, const float* __restrict__ b2, const float* __restrict__ bn2,
                      float* __restrict__ scores) {
  __shared__ float xs[64 * 68];
  __shared__ float ws[64 * 68];
  __shared__ float s0s[64 * 68];
  __shared__ float s1s[64 * 20];
  int row0 = blockIdx.x * 64;
  int t = threadIdx.x;
  #pragma unroll
  for (int i = 0; i < 4; ++i) {
    int q = t + i * 256, r = q >> 4, c = (q & 15) * 4;
    *(float4*)(xs + r * 68 + c) = *(const float4*)(x + (size_t)(row0 + r) * 64 + c);
    *(float4*)(ws + r * 68 + c) = *(const float4*)(w0 + r * 64 + c);
  }
  __syncthreads();
  int tx = t & 15, ty = t >> 4;
  float acc[4][4] = {};
  for (int f = 0; f < 64; f += 4) {
    float4 xv[4], wv[4];
    #pragma unroll
    for (int ri = 0; ri < 4; ++ri) xv[ri] = *(const float4*)(xs + (ty * 4 + ri) * 68 + f);
    #pragma unroll
    for (int ci = 0; ci < 4; ++ci) wv[ci] = *(const float4*)(ws + (tx + 16 * ci) * 68 + f);
    #pragma unroll
    for (int ri = 0; ri < 4; ++ri)
      #pragma unroll
      for (int ci = 0; ci < 4; ++ci)
        acc[ri][ci] += xv[ri].x * wv[ci].x + xv[ri].y * wv[ci].y +
                       xv[ri].z * wv[ci].z + xv[ri].w * wv[ci].w;
  }
  #pragma unroll
  for (int ri = 0; ri < 4; ++ri)
    #pragma unroll
    for (int ci = 0; ci < 4; ++ci) {
      int c = tx + 16 * ci;
      float sc = bn0[c] * rsqrtf(bn0[192 + c] + EPSF);
      float v = (acc[ri][ci] + b0[c] - bn0[128 + c]) * sc + bn0[64 + c];
      s0s[(ty * 4 + ri) * 68 + c] = fmaxf(v, 0.f);
    }
  __syncthreads();
  {
    int rl = t & 63, j0 = t >> 6;
    #pragma unroll
    for (int i = 0; i < 4; ++i) {
      int j = j0 + 4 * i;
      float s = b1[j];
      const float* wr = w1 + j * 64;
      #pragma unroll 16
      for (int c = 0; c < 64; ++c) s += s0s[rl * 68 + c] * wr[c];
      float sc = bn1[j] * rsqrtf(bn1[48 + j] + EPSF);
      s = (s - bn1[32 + j]) * sc + bn1[16 + j];
      s1s[rl * 20 + j] = fmaxf(s, 0.f);
    }
  }
  __syncthreads();
  if (t < 64) {
    float s = b2[0];
    #pragma unroll
    for (int o = 0; o < 16; ++o) s += s1s[t * 20 + o] * w2[o];
    float sc = bn2[0] * rsqrtf(bn2[3] + EPSF);
    s = (s - bn2[2]) * sc + bn2[1];
    scores[row0 + t] = fmaxf(s, 0.f);
  }
}

// ---- top-k (k=16) ----
__global__ void k_topk2(const float* __restrict__ scores, int* __restrict__ idx,
                        float* __restrict__ out_idx) {
  int b = blockIdx.x, t = threadIdx.x;
  float v[8];
  int base = b * NN;
  #pragma unroll
  for (int u = 0; u < 8; ++u) v[u] = scores[base + t + 256 * u];
  __shared__ float wvs[4];
  __shared__ int wis[4];
  __shared__ int winner;
  unsigned taken = 0;
  for (int r = 0; r < TOPK; ++r) {
    float best = -1e30f; int bi = 1 << 30;
    #pragma unroll
    for (int u = 0; u < 8; ++u) {
      if (!((taken >> u) & 1)) {
        float vv = v[u]; int ii = t + 256 * u;
        if (vv > best || (vv == best && ii < bi)) { best = vv; bi = ii; }
      }
    }
    for (int off = 32; off; off >>= 1) {
      float ov = __shfl_xor(best, off);
      int oi = __shfl_xor(bi, off);
      if (ov > best || (ov == best && oi < bi)) { best = ov; bi = oi; }
    }
    if ((t & 63) == 0) { wvs[t >> 6] = best; wis[t >> 6] = bi; }
    __syncthreads();
    if (t == 0) {
      float B = wvs[0]; int I = wis[0];
      #pragma unroll
      for (int q = 1; q < 4; ++q)
        if (wvs[q] > B || (wvs[q] == B && wis[q] < I)) { B = wvs[q]; I = wis[q]; }
      winner = I;
      idx[b * TOPK + r] = I;
      out_idx[b * TOPK + r] = (float)I;
    }
    __syncthreads();
    int w = winner;
    if ((w & 255) == t) taken |= 1u << (w >> 8);
  }
}

// ---------------- ball query + 3 conv stages; grid z=4 splits conv2 (128 ch
// per block, 4 lanes/ch); ball query/conv0/conv1 duplicated (cheap). ----
__global__ void __launch_bounds__(512)
k_group(const float* __restrict__ inp, const int* __restrict__ idx,
        const float* __restrict__ w0, const float* __restrict__ b0, const float* __restrict__ bn0,
        const float* __restrict__ w1, const float* __restrict__ b1, const float* __restrict__ bn1,
        const float* __restrict__ w2, const float* __restrict__ b2, const float* __restrict__ bn2,
        float* __restrict__ r2g) {
  __shared__ int swave[8 * 64];
  __shared__ int scnt[8];
  __shared__ int gidx[NSAMP];
  __shared__ __attribute__((aligned(16))) float gsh[65 * DD];
  __shared__ __attribute__((aligned(16))) float r0[128];
  __shared__ __attribute__((aligned(16))) float r1[256];
  int k = blockIdx.x, b = blockIdx.y, z = blockIdx.z;
  int t = threadIdx.x;
  int lane = t & 63, w = t >> 6;
  int qn = idx[b * TOPK + k];
  const float* px = inp + (size_t)b * DD * NN;
  float qx = px[qn], qy = px[NN + qn], qz = px[2 * NN + qn];
  {
    int cnt = 0;
    #pragma unroll
    for (int i = 0; i < 4; ++i) {
      int n = w * 256 + i * 64 + lane;
      float dx = px[n] - qx, dy = px[NN + n] - qy, dz = px[2 * NN + n] - qz;
      bool flag = (dx * dx + dy * dy + dz * dz <= R2);
      unsigned long long m = __ballot(flag);
      int pos = cnt + __popcll(m & ((1ull << lane) - 1ull));
      if (flag && pos < NSAMP) swave[w * 64 + pos] = n;
      cnt += (int)__popcll(m);
    }
    if (lane == 0) scnt[w] = cnt < NSAMP ? cnt : NSAMP;
  }
  __syncthreads();
  if (t < NSAMP) {
    int run = 0, val = -1;
    #pragma unroll
    for (int ww = 0; ww < 8; ++ww) {
      int c = scnt[ww];
      int loc = t - run;
      if (loc >= 0 && loc < c) val = swave[ww * 64 + loc];
      run += c;
    }
    gidx[t] = val;
  }
  __syncthreads();
  if (t < NSAMP) {
    int g0 = gidx[0];
    int gt = gidx[t];
    gidx[t] = (gt < 0) ? g0 : gt;
  }
  __syncthreads();
  if (t < 65 * DD) {
    int p = t / DD, d = t - p * DD;
    int n = (p == 0) ? qn : gidx[p - 1];
    gsh[t] = px[d * NN + n];
  }
  __syncthreads();
  {
    int c = t >> 2, part = t & 3;
    const float2* wr = (const float2*)(w0 + c * 390 + part * 98);
    const float2* gr = (const float2*)(gsh + part * 98);
    int n2 = (part == 3) ? 48 : 49;
    float s = 0.f;
    #pragma unroll 7
    for (int i = 0; i < n2; ++i) {
      float2 a = gr[i], ww = wr[i];
      s += a.x * ww.x + a.y * ww.y;
    }
    s += __shfl_xor(s, 1);
    s += __shfl_xor(s, 2);
    if (part == 0) {
      s += b0[c];
      float sc = bn0[c] * rsqrtf(bn0[384 + c] + EPSF);
      s = (s - bn0[256 + c]) * sc + bn0[128 + c];
      r0[c] = fmaxf(s, 0.f);
    }
  }
  __syncthreads();
  {
    int c = t >> 1, part = t & 1;
    const float4* wr = (const float4*)(w1 + c * 128 + part * 64);
    const float4* rr = (const float4*)(r0 + part * 64);
    float s0 = 0.f, s1 = 0.f, s2 = 0.f, s3 = 0.f;
    #pragma unroll 8
    for (int o = 0; o < 16; ++o) {
      float4 a = rr[o], ww = wr[o];
      s0 += a.x * ww.x; s1 += a.y * ww.y; s2 += a.z * ww.z; s3 += a.w * ww.w;
    }
    float s = (s0 + s1) + (s2 + s3);
    s += __shfl_xor(s, 1);
    if (part == 0) {
      s += b1[c];
      float sc = bn1[c] * rsqrtf(bn1[768 + c] + EPSF);
      s = (s - bn1[512 + c]) * sc + bn1[256 + c];
      r1[c] = fmaxf(s, 0.f);
    }
  }
  __syncthreads();
  {
    int c = z * 128 + (t >> 2), part = t & 3;
    const float4* wr = (const float4*)(w2 + c * 256 + part * 64);
    const float4* rr = (const float4*)(r1 + part * 64);
    float s0 = 0.f, s1 = 0.f, s2 = 0.f, s3 = 0.f;
    #pragma unroll 8
    for (int o = 0; o < 16; ++o) {
      float4 a = rr[o], ww = wr[o];
      s0 += a.x * ww.x; s1 += a.y * ww.y; s2 += a.z * ww.z; s3 += a.w * ww.w;
    }
    float s = (s0 + s1) + (s2 + s3);
    s += __shfl_xor(s, 1);
    s += __shfl_xor(s, 2);
    if (part == 0) {
      s += b2[c];
      float sc = bn2[c] * rsqrtf(bn2[1536 + c] + EPSF);
      s = (s - bn2[1024 + c]) * sc + bn2[512 + c];
      r2g[b * 8192 + c * TOPK + k] = fmaxf(s, 0.f);
    }
  }
}

// ------- FC layer 1: batched GEMV, split-K 8 ----
__global__ void __launch_bounds__(256)
k_fl2(const float* __restrict__ hin, const float* __restrict__ w,
      float* __restrict__ part) {
  __shared__ float hs[8 * 1032];
  int j0 = blockIdx.x * 16;
  int kc = blockIdx.y * 1024;
  int t = threadIdx.x;
  int jj = t >> 4, l = t & 15;
  #pragma unroll
  for (int i = 0; i < 8; ++i) {
    int idx = t + i * 256;
    int b = idx >> 8, off = (idx & 255) * 4;
    *(float4*)(hs + b * 1032 + off) = *(const float4*)(hin + (size_t)b * 8192 + kc + off);
  }
  __syncthreads();
  const float* wr = w + (size_t)(j0 + jj) * 8192 + kc;
  float acc[8] = {};
  #pragma unroll
  for (int k = 0; k < 16; ++k) {
    float4 wv = *(const float4*)(wr + l * 4 + k * 64);
    #pragma unroll
    for (int b = 0; b < 8; ++b) {
      float4 hv = *(const float4*)(hs + b * 1032 + l * 4 + k * 64);
      acc[b] += wv.x * hv.x + wv.y * hv.y + wv.z * hv.z + wv.w * hv.w;
    }
  }
  #pragma unroll
  for (int b = 0; b < 8; ++b) {
    #pragma unroll
    for (int off = 1; off < 16; off <<= 1) acc[b] += __shfl_xor(acc[b], off);
  }
  if (l == 0) {
    #pragma unroll
    for (int b = 0; b < 8; ++b)
      part[((size_t)blockIdx.y * 8 + b) * 1024 + j0 + jj] = acc[b];
  }
}

// ------- combine 8 split-K partials + bias + BN + ReLU -> h1g ----
__global__ void k_flc(const float* __restrict__ part, const float* __restrict__ bias,
                      const float* __restrict__ bn, float* __restrict__ hout) {
  int i = blockIdx.x * 256 + threadIdx.x;  // 0..8191
  int b = i >> 10, j = i & 1023;
  float s = bias[j];
  #pragma unroll
  for (int ks = 0; ks < 8; ++ks) s += part[((size_t)ks * 8 + b) * 1024 + j];
  float sc = bn[j] * rsqrtf(bn[3 * 1024 + j] + EPSF);
  s = (s - bn[2 * 1024 + j]) * sc + bn[1024 + j];
  hout[i] = fmaxf(s, 0.f);
}

// ------- FC layer 2: batched GEMV, split-K 4 ----
__global__ void __launch_bounds__(256)
k_fl3(const float* __restrict__ hin, const float* __restrict__ w,
      float* __restrict__ part) {
  __shared__ float hs[8 * 264];
  int j0 = blockIdx.x * 16;
  int kc = blockIdx.y * 256;
  int t = threadIdx.x;
  int jj = t >> 4, l = t & 15;
  #pragma unroll
  for (int i = 0; i < 2; ++i) {
    int idx = t + i * 256;
    int b = idx >> 6, off = (idx & 63) * 4;
    *(float4*)(hs + b * 264 + off) = *(const float4*)(hin + (size_t)b * 1024 + kc + off);
  }
  __syncthreads();
  const float* wr = w + (size_t)(j0 + jj) * 1024 + kc;
  float acc[8] = {};
  #pragma unroll
  for (int k = 0; k < 4; ++k) {
    float4 wv = *(const float4*)(wr + l * 4 + k * 64);
    #pragma unroll
    for (int b = 0; b < 8; ++b) {
      float4 hv = *(const float4*)(hs + b * 264 + l * 4 + k * 64);
      acc[b] += wv.x * hv.x + wv.y * hv.y + wv.z * hv.z + wv.w * hv.w;
    }
  }
  #pragma unroll
  for (int b = 0; b < 8; ++b) {
    #pragma unroll
    for (int off = 1; off < 16; off <<= 1) acc[b] += __shfl_xor(acc[b], off);
  }
  if (l == 0) {
    #pragma unroll
    for (int b = 0; b < 8; ++b)
      part[((size_t)blockIdx.y * 8 + b) * 512 + j0 + jj] = acc[b];
  }
}

// ------- combine 4 split-K partials + bias + BN + ReLU -> out ----
__global__ void k_flc2(const float* __restrict__ part, const float* __restrict__ bias,
                       const float* __restrict__ bn, float* __restrict__ hout) {
  int i = blockIdx.x * 256 + threadIdx.x;  // 0..4095
  int b = i >> 9, j = i & 511;
  float s = bias[j];
  #pragma unroll
  for (int ks = 0; ks < 4; ++ks) s += part[((size_t)ks * 8 + b) * 512 + j];
  float sc = bn[j] * rsqrtf(bn[3 * 512 + j] + EPSF);
  s = (s - bn[2 * 512 + j]) * sc + bn[512 + j];
  hout[i] = fmaxf(s, 0.f);
}

extern "C" void kernel_launch(void* const* d_in, const int* in_sizes, int n_in,
                              void* d_out, int out_size, void* d_ws, size_t ws_size,
                              hipStream_t stream) {
  const float* sv      = (const float*)d_in[0];
  const float* inp     = (const float*)d_in[1];
  const float* tl_win  = (const float*)d_in[2];
  const float* tl_bin  = (const float*)d_in[3];
  const float* tl_wout = (const float*)d_in[4];
  const float* tl_bout = (const float*)d_in[5];
  const float* tl_w1   = (const float*)d_in[6];
  const float* tl_b1   = (const float*)d_in[7];
  const float* tl_w2   = (const float*)d_in[8];
  const float* tl_b2   = (const float*)d_in[9];
  const float* tl_ln1g = (const float*)d_in[10];
  const float* tl_ln1b = (const float*)d_in[11];
  const float* tl_ln2g = (const float*)d_in[12];
  const float* tl_ln2b = (const float*)d_in[13];
  const float* fg_w0   = (const float*)d_in[14];
  const float* fg_b0   = (const float*)d_in[15];
  const float* fg_w1   = (const float*)d_in[16];
  const float* fg_b1   = (const float*)d_in[17];
  const float* fg_w2   = (const float*)d_in[18];
  const float* fg_b2   = (const float*)d_in[19];
  const float* fbn0    = (const float*)d_in[20];
  const float* fbn1    = (const float*)d_in[21];
  const float* fbn2    = (const float*)d_in[22];
  const float* rc_w0   = (const float*)d_in[23];
  const float* rc_b0   = (const float*)d_in[24];
  const float* rc_w1   = (const float*)d_in[25];
  const float* rc_b1   = (const float*)d_in[26];
  const float* rc_w2   = (const float*)d_in[27];
  const float* rc_b2   = (const float*)d_in[28];
  const float* rbn0    = (const float*)d_in[29];
  const float* rbn1    = (const float*)d_in[30];
  const float* rbn2    = (const float*)d_in[31];
  const float* fl_w0   = (const float*)d_in[32];
  const float* fl_b0   = (const float*)d_in[33];
  const float* fl_w1   = (const float*)d_in[34];
  const float* fl_b1   = (const float*)d_in[35];
  const float* lbn0    = (const float*)d_in[36];
  const float* lbn1    = (const float*)d_in[37];
  (void)in_sizes; (void)n_in; (void)out_size; (void)ws_size;

  float* wsp = (float*)d_ws;
  float* x      = wsp;                        // B*N*F      = 1048576
  float* qkv    = x + BB * NN * FF;           // 3145728-float region
  float* a      = qkv + BB * NN * 192;        // B*N*F      = 1048576
  float* scores = a + BB * NN * FF;           // B*N        = 16384
  int*   idxb   = (int*)(scores + BB * NN);   // B*TOPK     = 128
  float* r2g    = (float*)(idxb + BB * TOPK); // B*8192     = 65536
  float* h1g    = r2g + BB * 8192;            // B*1024     = 8192
  // FFN weight image: [l][chg][4 planes][4096 u16] = 1M u16 = 2MB
  unsigned short* img = (unsigned short*)(h1g + BB * 1024);
  // qkv/proj weight hi/lo planes (after img)
  unsigned short* wqh = img + (size_t)NLAYER * 32 * 4 * 4096;
  unsigned short* wql = wqh + NLAYER * 192 * 64;
  unsigned short* woh = wql + NLAYER * 192 * 64;
  unsigned short* wol = woh + NLAYER * 64 * 64;
  // qkv region carve-out: Q fp32 (1M floats) | kp bf16 (1M u16) | vp bf16 (1M u16)
  float* qbuf = qkv;
  unsigned short* kp = (unsigned short*)(qkv + BB * NN * FF);
  unsigned short* vp = kp + (size_t)BB * NHEAD * NN * HD;
  float* part = qkv;        // FFN & FC-1 split-K partials reuse qkv region
  float* part2 = qkv + 65536;  // FC-2 partials (4*8*512 floats)

  float* out = (float*)d_out;  // fp32: h at [0,4096), idx-as-float at [4096,4224)

  k_prep<<<(BB * NN * FF) / 256, 256, 0, stream>>>(sv, x, tl_w1, tl_w2, img,
                                                   tl_win, wqh, wql, tl_wout, woh, wol);

  for (int l = 0; l < NLAYER; ++l) {
    k_qkv4<<<dim3(BB * NN / 64, 3), 256, 0, stream>>>(x, wqh + l * 192 * 64,
                                                      wql + l * 192 * 64, tl_bin + l * 192,
                                                      qbuf, (uint4*)kp, (uint4*)vp);
    k_attn11<<<dim3(NN / 64, NHEAD, BB), 256, 0, stream>>>(qbuf, (const uint4*)kp,
                                                           (const unsigned*)vp, a);
    k_proj3<<<BB * NN / 64, 256, 0, stream>>>(a, woh + l * 64 * 64, wol + l * 64 * 64,
                                              tl_bout + l * FF,
                                              tl_ln1g + l * FF, tl_ln1b + l * FF, x);
    k_ffn8<<<dim3(BB * NN / 128, 4), 256, 0, stream>>>(x, (const char*)(img + (size_t)l * 524288),
                                                       tl_b1 + l * 2048, part);
    k_ffn_ln<<<BB * NN / 4, 256, 0, stream>>>(part, tl_b2 + l * FF,
                                              tl_ln2g + l * FF, tl_ln2b + l * FF, x);
  }

  k_fg2<<<BB * NN / 64, 256, 0, stream>>>(x, fg_w0, fg_b0, fbn0, fg_w1, fg_b1, fbn1,
                                          fg_w2, fg_b2, fbn2, scores);
  k_topk2<<<BB, 256, 0, stream>>>(scores, idxb, out + BB * 512);
  k_group<<<dim3(TOPK, BB, 4), 512, 0, stream>>>(inp, idxb, rc_w0, rc_b0, rbn0,
                                                 rc_w1, rc_b1, rbn1, rc_w2, rc_b2, rbn2, r2g);
  k_fl2<<<dim3(64, 8), 256, 0, stream>>>(r2g, fl_w0, part);
  k_flc<<<32, 256, 0, stream>>>(part, fl_b0, lbn0, h1g);
  k_fl3<<<dim3(32, 4), 256, 0, stream>>>(h1g, fl_w1, part2);
  k_flc2<<<16, 256, 0, stream>>>(part2, fl_b1, lbn1, out);
}